// Round 1
// baseline (658.886 us; speedup 1.0000x reference)
//
#include <hip/hip_runtime.h>

// ProdAt: x[B=16384, S*L = 128*64 = 8192] fp32 -> out[B, 128] fp32,
// out[b,s] = prod_{l<64} x[b, s*64+l].
//
// Memory-bound (512 MiB read / 8 MiB write). Strategy: wave-aligned float4
// loads (16 B/lane * 64 lanes = 1 KiB per wave load, fully coalesced).
// A wave's 256 consecutive floats = exactly 4 segments (rows are 8192 floats,
// a multiple of 256, so chunks never straddle rows/segments). Per-lane product
// of its 4 elements, then 16-lane shfl_xor product tree, one store per segment.

__global__ __launch_bounds__(256) void prodat_kernel(
    const float4* __restrict__ x4, float* __restrict__ out, long long n4) {
    const long long tid    = (long long)blockIdx.x * blockDim.x + threadIdx.x;
    const long long stride = (long long)gridDim.x * blockDim.x;
    const int lane = threadIdx.x & 63;

    for (long long i = tid; i < n4; i += stride) {
        float4 v = x4[i];
        float p = (v.x * v.y) * (v.z * v.w);
        // reduce product across the 16-lane group covering one segment
        p *= __shfl_xor(p, 1);
        p *= __shfl_xor(p, 2);
        p *= __shfl_xor(p, 4);
        p *= __shfl_xor(p, 8);
        if ((lane & 15) == 0) {
            // float4 index i -> segment (flat out) index i/16; writing lane has i%16==0
            out[i >> 4] = p;
        }
    }
}

extern "C" void kernel_launch(void* const* d_in, const int* in_sizes, int n_in,
                              void* d_out, int out_size, void* d_ws, size_t ws_size,
                              hipStream_t stream) {
    const float4* x4 = (const float4*)d_in[0];
    float* out = (float*)d_out;
    const long long n_elems = (long long)in_sizes[0];   // 16384 * 8192
    const long long n4 = n_elems >> 2;                  // 33,554,432 float4s

    const int block = 256;
    const int grid = 4096;  // 1,048,576 threads -> exactly 32 float4s/thread
    prodat_kernel<<<grid, block, 0, stream>>>(x4, out, n4);
}

// Round 3
// 650.300 us; speedup vs baseline: 1.0132x; 1.0132x over previous
//
#include <hip/hip_runtime.h>

// ProdAt: x[B=16384, 128*64=8192] fp32 -> out[B,128] fp32,
// out[b,s] = prod_{l<64} x[b, s*64+l].
//
// Memory-bound: 512 MiB read / 8 MiB write -> ~85 us floor @ 6.3 TB/s.
// Wave-aligned 16B loads (16 B/lane), 16-lane shfl_xor product tree,
// one store per segment. This revision:
//  - compile-time trip count (32) and stride so the compiler can unroll
//  - #pragma unroll 8: 8 independent global_load_dwordx4 in flight per wave
//    before the first vmcnt wait (MLP, instead of load->wait->use per iter)
//  - nontemporal loads: 512 MiB single-use stream, skip L2 pollution
//  - native ext_vector_type for the load (HIP_vector_type struct is rejected
//    by __builtin_nontemporal_load)

typedef float floatx4 __attribute__((ext_vector_type(4)));

#define GRID   4096
#define BLOCK  256
#define NTHREADS ((long long)GRID * BLOCK)       // 1,048,576
#define ITERS  32                                 // 33,554,432 float4s total

__global__ __launch_bounds__(BLOCK) void prodat_kernel(
    const floatx4* __restrict__ x4, float* __restrict__ out) {
    const long long tid = (long long)blockIdx.x * BLOCK + threadIdx.x;
    const int lane = threadIdx.x & 63;

#pragma unroll 8
    for (int it = 0; it < ITERS; ++it) {
        const long long i = tid + (long long)it * NTHREADS;
        floatx4 v = __builtin_nontemporal_load(&x4[i]);
        float p = (v.x * v.y) * (v.z * v.w);
        // product across the 16-lane group covering one 64-elem segment
        p *= __shfl_xor(p, 1);
        p *= __shfl_xor(p, 2);
        p *= __shfl_xor(p, 4);
        p *= __shfl_xor(p, 8);
        if ((lane & 15) == 0) {
            out[i >> 4] = p;   // float4 idx -> segment idx
        }
    }
}

extern "C" void kernel_launch(void* const* d_in, const int* in_sizes, int n_in,
                              void* d_out, int out_size, void* d_ws, size_t ws_size,
                              hipStream_t stream) {
    const floatx4* x4 = (const floatx4*)d_in[0];
    float* out = (float*)d_out;
    // in_sizes[0] == 16384*8192 == GRID*BLOCK*ITERS*4, exact — no tail.
    prodat_kernel<<<GRID, BLOCK, 0, stream>>>(x4, out);
}